// Round 9
// baseline (452.089 us; speedup 1.0000x reference)
//
#include <hip/hip_runtime.h>

#define N_TOT 65536
#define K_CB  2048
#define D_DIM 256
#define HW    4096       // H*W
#define DHW   1048576    // D*H*W

typedef _Float16 half8 __attribute__((ext_vector_type(8)));
typedef _Float16 half4v __attribute__((ext_vector_type(4)));
typedef float f32x16 __attribute__((ext_vector_type(16)));

// ws layout (4-byte element offsets):
//   cb2      [0, 2048)          float (np-pairwise ||c_k||^2)
//   counts   [2048, 4096)       int
//   sse      [4096]             float
//   z2       [4352, 69888)      float (np-pairwise ||z_n||^2)
//   rowmin_g [69888, 200960)    u64 x 65536
//   c_hi     [200960, 463104)   fp16 x 524288  (codebook * 2^14, hi)
//   c_lo     [463104, 725248)   fp16 x 524288  (lo)
// z splits live in d_out[0..16777216) floats (overwritten later by q), in
// FRAGMENT-MAJOR layout (dense per-wave MFMA A-loads, no LDS for A):
//   element (n,d) at half-offset rb*8192 + s*512 + lane*8 + e, where
//   rb=n>>5, s=d>>4, lane=(n&31)|(((d>>3)&1)<<5), e=d&7.
//   zh = (fp16*)d_out (z*2^11 hi), zl follows (lo).

__device__ __forceinline__ void gload_lds16(const void* g, void* l) {
    __builtin_amdgcn_global_load_lds((const __attribute__((address_space(1))) void*)g,
                                     (__attribute__((address_space(3))) void*)l, 16, 0, 0);
}

// ---------- codebook norms (np-pairwise, verified exact) + zero counts/sse ----------
__device__ __forceinline__ float pw128_sq(const float* __restrict__ base, int stride) {
    #pragma clang fp contract(off)
    float r[8];
    #pragma unroll
    for (int j = 0; j < 8; ++j) { float v = base[j * stride]; r[j] = v * v; }
    for (int i = 8; i < 128; i += 8) {
        #pragma unroll
        for (int j = 0; j < 8; ++j) { float v = base[(i + j) * stride]; r[j] += v * v; }
    }
    return ((r[0] + r[1]) + (r[2] + r[3])) + ((r[4] + r[5]) + (r[6] + r[7]));
}

__global__ void cbnorm_zero_kernel(const float* __restrict__ cb, float* __restrict__ cb2,
                                   int* __restrict__ counts, float* __restrict__ sse) {
    #pragma clang fp contract(off)
    int k = blockIdx.x * 256 + threadIdx.x;
    const float* row = cb + (size_t)k * D_DIM;
    cb2[k] = pw128_sq(row, 1) + pw128_sq(row + 128, 1);
    counts[k] = 0;
    if (k == 0) *sse = 0.f;
}

__global__ void split_c_kernel(const float* __restrict__ cb,
                               _Float16* __restrict__ ch, _Float16* __restrict__ cl) {
    int e = (blockIdx.x * 256 + threadIdx.x) * 4;
    float4 v = *(const float4*)(cb + e);
    float xs[4] = {v.x, v.y, v.z, v.w};
    half4v hh, hl;
    #pragma unroll
    for (int u = 0; u < 4; ++u) {
        float x = xs[u] * 16384.0f;                  // 2^14 exact
        _Float16 hv = (_Float16)x;
        hh[u] = hv;
        hl[u] = (_Float16)(x - (float)hv);           // exact sub, then RTNE
    }
    *(half4v*)(ch + e) = hh;
    *(half4v*)(cl + e) = hl;
}

// ---------- fused: z transpose+split (frag-major), np-exact z2, rowmin_g init ----------
// Block: 32 rows x 256 d. 2048 blocks x 256 threads.
__global__ void fused_z_kernel(const float* __restrict__ z,
                               _Float16* __restrict__ zh, _Float16* __restrict__ zl,
                               float* __restrict__ z2,
                               unsigned long long* __restrict__ rowmin_g) {
    __shared__ __align__(16) float lt[256 * 33];   // lt[d][n], pad stride 33
    __shared__ float rj[512];                      // [n(32)][half(2)][j(8)]
    __shared__ float hh[64];                       // [half(2)][n(32)]
    int t = threadIdx.x;
    int n0 = blockIdx.x * 32;
    int b = n0 >> 12, s0 = n0 & 4095;
    const float* zb = z + (size_t)b * DHW + s0;

    #pragma unroll
    for (int v = 0; v < 8; ++v) {                  // 2048 float4 loads
        int f = v * 256 + t;
        int d = f >> 3, nch = f & 7;
        float4 val = *(const float4*)(zb + (size_t)d * HW + nch * 4);
        lt[d * 33 + nch * 4 + 0] = val.x;
        lt[d * 33 + nch * 4 + 1] = val.y;
        lt[d * 33 + nch * 4 + 2] = val.z;
        lt[d * 33 + nch * 4 + 3] = val.w;
    }
    __syncthreads();

    // np-pairwise partials: thread (n, j) accumulates r_j over i*8+j, both halves.
    {
        #pragma clang fp contract(off)
        int n = t & 31, j = t >> 5;                // j in 0..7
        #pragma unroll
        for (int hf = 0; hf < 2; ++hf) {
            float r = 0.f;
            #pragma unroll
            for (int i = 0; i < 16; ++i) {
                float v = lt[(hf * 128 + i * 8 + j) * 33 + n];
                r += v * v;
            }
            rj[n * 16 + hf * 8 + j] = r;
        }
    }

    // split writes, FRAGMENT-MAJOR: wave wv handles slice s=v*4+wv; lane ln
    // writes the 8 halfs of (row n=ln&31, d0=s*16+(ln>>5)*8) -> dense 1KB/wave.
    {
        int wv = t >> 6, ln = t & 63;
        int rb = n0 >> 5;
        #pragma unroll
        for (int v = 0; v < 4; ++v) {
            int s = v * 4 + wv;                    // slice 0..15
            int n = ln & 31;
            int d0 = s * 16 + (ln >> 5) * 8;
            half8 hv, lv;
            #pragma unroll
            for (int u = 0; u < 8; ++u) {
                float x = lt[(d0 + u) * 33 + n] * 2048.0f;   // 2^11 exact
                _Float16 h = (_Float16)x;
                hv[u] = h;
                lv[u] = (_Float16)(x - (float)h);
            }
            size_t off = (size_t)rb * 8192 + s * 512 + ln * 8;
            *(half8*)(zh + off) = hv;
            *(half8*)(zl + off) = lv;
        }
    }
    __syncthreads();

    if (t < 64) {                                  // np combine per (n, half)
        #pragma clang fp contract(off)
        int n = t & 31, hf = t >> 5;
        const float* r = &rj[n * 16 + hf * 8];
        hh[hf * 32 + n] = ((r[0] + r[1]) + (r[2] + r[3])) + ((r[4] + r[5]) + (r[6] + r[7]));
    }
    __syncthreads();
    if (t < 32) {
        #pragma clang fp contract(off)
        z2[n0 + t] = hh[t] + hh[32 + t];           // half0 + half1, np order
        rowmin_g[n0 + t] = ~0ull;
    }
}

// ---------- MFMA distance + argmin (256x128 tile: dedup'd A, amortized B) ----------
// Block: 256 rows x 128 codes, 256 threads; wave w owns rows [w*64, w*64+64) x ALL
// 128 cols (acc[2][4], 128 AGPRs). Traffic per 256x128 tile: A 32 KB (each wave
// loads ONLY its own rows -- r8's 2x wn-duplication eliminated) + B 16 KB = 48 KB,
// HALF of r8's 96 KB per output area. Delivery-bound analysis (r0-r8: MfmaUtil
// pinned 27-33% across all schedules/occupancies) says bytes/output is the lever.
// A loads are JIT inside compute (dense 1KB wave-loads from frag-major zh/zl,
// base+imm-offset addressing). B double-buffered via gload_lds, ONE __syncthreads
// per tile (r8 proven skeleton; asm barriers regressed in r7).
// Epilogue: each row's 128 cols live in one wave -> pure shuffle argmin reduce,
// no LDS scratch, no barriers.
// acc = 2^25*dot; m2 = acc*2^-24 exact; score = (z2+c2) - m2 (matches np fp32).

__device__ __forceinline__ unsigned long long kmin_xor(unsigned long long key, int m) {
    unsigned lo = (unsigned)key, hi = (unsigned)(key >> 32);
    unsigned olo = __shfl_xor(lo, m);
    unsigned ohi = __shfl_xor(hi, m);
    unsigned long long o = ((unsigned long long)ohi << 32) | olo;
    return (o < key) ? o : key;
}

__launch_bounds__(256, 3)
__global__ void argmin_mfma_kernel(const _Float16* __restrict__ zhf, const _Float16* __restrict__ zlf,
                                   const _Float16* __restrict__ ch, const _Float16* __restrict__ cl,
                                   const float* __restrict__ cb2, const float* __restrict__ z2arr,
                                   unsigned long long* __restrict__ rowmin_g) {
    __shared__ __align__(16) char lds_raw[32768];
    _Float16* b0 = (_Float16*)lds_raw;               // 128 codes x 64 k (16B-unit XOR swizzle)
    _Float16* b1 = (_Float16*)(lds_raw + 16384);

    int t = threadIdx.x;
    // bijective XCD swizzle: 4096 blocks, 512 per XCD; ct (16 col-tiles) fastest
    // within chunk so the B-panels (2 MB split codebook) stay L2-resident per XCD.
    int bid = blockIdx.x;
    int swz = (bid & 7) * 512 + (bid >> 3);
    int r0 = (swz >> 4) * 256;
    int c0 = (swz & 15) * 128;
    int w = t >> 6, lane = t & 63;
    int l31 = lane & 31, l5 = lane >> 5;

    f32x16 acc[2][4];
    #pragma unroll
    for (int i = 0; i < 2; ++i)
        #pragma unroll
        for (int j = 0; j < 4; ++j)
            #pragma unroll
            for (int r = 0; r < 16; ++r) acc[i][j][r] = 0.f;

    float c2v[4];
    #pragma unroll
    for (int j = 0; j < 4; ++j)
        c2v[j] = cb2[c0 + j * 32 + l31];

    // A-fragment bases (halfs): row-blocks rb = (r0>>5) + w*2 + i; lane-dense.
    size_t abase0 = (size_t)((r0 >> 5) + w * 2) * 8192 + (size_t)lane * 8;
    size_t abase1 = abase0 + 8192;

    // stage B tile kt into nb (4 gload_lds16/thread, inverse-swizzled source)
    auto stage_B = [&](int kt, _Float16* nb) {
        const _Float16* bsrc = ((kt >> 2) == 1) ? cl : ch;
        int koff = (kt & 3) * 64;
        #pragma unroll
        for (int v = 0; v < 4; ++v) {            // 1024 16B-units
            int p = v * 256 + t;
            int row = p >> 3;
            int ku = (p & 7) ^ (row & 7);        // inverse swizzle on global source
            gload_lds16(bsrc + (size_t)((c0 + row) * 256 + koff + ku * 8), nb + p * 8);
        }
    };
    // compute one K-tile: A-frags JIT (base + compile-time offsets), B from LDS
    auto compute = [&](int kt, const _Float16* lb) {
        const _Float16* as = (kt < 8) ? zhf : zlf;
        const _Float16* a0p = as + abase0 + (kt & 3) * 2048;
        const _Float16* a1p = as + abase1 + (kt & 3) * 2048;
        #pragma unroll
        for (int ks = 0; ks < 4; ++ks) {
            half8 af0 = *(const half8*)(a0p + ks * 512);
            half8 af1 = *(const half8*)(a1p + ks * 512);
            #pragma unroll
            for (int j = 0; j < 4; ++j) {
                int row = j * 32 + l31;
                int ku  = (ks * 2 + l5) ^ (row & 7);
                half8 bf = *(const half8*)(lb + row * 64 + ku * 8);
                acc[0][j] = __builtin_amdgcn_mfma_f32_32x32x16_f16(af0, bf, acc[0][j], 0, 0, 0);
                acc[1][j] = __builtin_amdgcn_mfma_f32_32x32x16_f16(af1, bf, acc[1][j], 0, 0, 0);
            }
        }
    };

    // prologue: stage tile 0, drain once
    stage_B(0, b0);
    __syncthreads();

    #pragma unroll 1
    for (int kp = 0; kp < 6; ++kp) {
        int kt1 = kp * 2 + 1;
        stage_B(kt1, b1);                        // issue next-tile B first
        compute(kp * 2, b0);
        __syncthreads();                         // drains everything; loads are old
        if (kp < 5) stage_B(kt1 + 1, b0);
        compute(kt1, b1);
        __syncthreads();
    }

    // Epilogue. D mapping (32x32): col=lane&31, row=(reg&3)+8*(reg>>2)+4*(lane>>5).
    // All 128 cols of a row are in this wave: per-lane j-min, then 5-level
    // shuffle-xor min over the 32-lane col group (masks <32 preserve l5/row).
    #pragma unroll
    for (int i = 0; i < 2; ++i) {
        #pragma unroll
        for (int rg = 0; rg < 16; ++rg) {
            int rowoff = (rg & 3) + 8 * (rg >> 2) + 4 * l5;
            int m = w * 64 + i * 32 + rowoff;
            float zz = z2arr[r0 + m];
            unsigned long long key = ~0ull;
            #pragma unroll
            for (int j = 0; j < 4; ++j) {
                float sc = (zz + c2v[j]) - acc[i][j][rg] * (1.0f / 16777216.0f);
                unsigned long long k2 = ((unsigned long long)__float_as_uint(sc) << 32)
                                      | (unsigned)(c0 + j * 32 + l31);
                key = (k2 < key) ? k2 : key;      // scores > 0: raw bits orderable
            }
            key = kmin_xor(key, 16);
            key = kmin_xor(key, 8);
            key = kmin_xor(key, 4);
            key = kmin_xor(key, 2);
            key = kmin_xor(key, 1);
            if (l31 == 0) atomicMin(&rowmin_g[r0 + m], key);
        }
    }
}

// ---------- gather q, SSE, histogram (vectorized: float4 along s for z and q) ----------
// Block: 64 rows x 256 d, 256 threads. Thread (sg=t&15 -> 4 n's, dg=t>>4 -> 16 d's).
// z read and q write are float4 along the spatial axis (16 lanes x 16B = 256B
// contiguous per d-row); codebook rows read as float4 (L2-resident 2MB).
// SSE stays per-element fp32 (z-q)^2 like the reference; only the partial-sum
// tree changed (wave shuffle + 1 atomic per block).
__global__ void gather_kernel(const float* __restrict__ z, const float* __restrict__ cb,
                              const unsigned long long* __restrict__ rowmin_g,
                              float* __restrict__ qout,
                              float* __restrict__ sse, int* __restrict__ counts) {
    __shared__ unsigned long long keys[64];
    __shared__ float red[4];
    int t = threadIdx.x;
    int n0 = blockIdx.x * 64;
    if (t < 64) {
        unsigned long long k = rowmin_g[n0 + t];
        keys[t] = k;
        atomicAdd(&counts[(int)(k & 0xFFFFFFFFull)], 1);
    }
    __syncthreads();

    int sg = (t & 15) * 4;                       // 4 consecutive n's
    int dg = t >> 4;                             // 16 d's per thread
    int b = n0 >> 12, s0 = (n0 & 4095) + sg;
    const float* zb = z + (size_t)b * DHW + s0;
    float*       qb = qout + (size_t)b * DHW + s0;
    const float* c0p = cb + (size_t)(unsigned)(keys[sg + 0] & 0xFFFFFFFFull) * D_DIM;
    const float* c1p = cb + (size_t)(unsigned)(keys[sg + 1] & 0xFFFFFFFFull) * D_DIM;
    const float* c2p = cb + (size_t)(unsigned)(keys[sg + 2] & 0xFFFFFFFFull) * D_DIM;
    const float* c3p = cb + (size_t)(unsigned)(keys[sg + 3] & 0xFFFFFFFFull) * D_DIM;

    float acc = 0.f;
    #pragma unroll
    for (int dd4 = 0; dd4 < 4; ++dd4) {
        int d = dg * 16 + dd4 * 4;
        float4 cA = *(const float4*)(c0p + d);
        float4 cB = *(const float4*)(c1p + d);
        float4 cC = *(const float4*)(c2p + d);
        float4 cD = *(const float4*)(c3p + d);
        float a0[4] = {cA.x, cA.y, cA.z, cA.w};
        float a1[4] = {cB.x, cB.y, cB.z, cB.w};
        float a2[4] = {cC.x, cC.y, cC.z, cC.w};
        float a3[4] = {cD.x, cD.y, cD.z, cD.w};
        #pragma unroll
        for (int u = 0; u < 4; ++u) {
            float4 zv = *(const float4*)(zb + (size_t)(d + u) * HW);
            float4 qv;
            qv.x = a0[u]; qv.y = a1[u]; qv.z = a2[u]; qv.w = a3[u];
            *(float4*)(qb + (size_t)(d + u) * HW) = qv;
            float e0 = zv.x - qv.x, e1 = zv.y - qv.y;
            float e2 = zv.z - qv.z, e3 = zv.w - qv.w;
            acc += e0 * e0 + e1 * e1 + e2 * e2 + e3 * e3;
        }
    }
    #pragma unroll
    for (int off = 32; off > 0; off >>= 1) acc += __shfl_down(acc, off, 64);
    if ((t & 63) == 0) red[t >> 6] = acc;
    __syncthreads();
    if (t == 0) atomicAdd(sse, (red[0] + red[1]) + (red[2] + red[3]));
}

__global__ void finalize_kernel(const float* __restrict__ sse, const int* __restrict__ counts,
                                float* __restrict__ out) {
    int t = threadIdx.x;
    float mse = *sse * (1.0f / 16777216.0f);   // /(N*D)
    if (t == 0) {
        out[16777216] = mse * 1.25f;  // loss
        out[16777217] = mse;          // codebook_loss
        out[16777218] = mse;          // commitment_loss
    }
    for (int i = t; i < 2048; i += 256) out[16777219 + i] = (float)counts[i];
}

extern "C" void kernel_launch(void* const* d_in, const int* in_sizes, int n_in,
                              void* d_out, int out_size, void* d_ws, size_t ws_size,
                              hipStream_t stream) {
    const float* z  = (const float*)d_in[0];
    const float* cb = (const float*)d_in[1];
    float* out = (float*)d_out;
    float* ws  = (float*)d_ws;

    float* cb2    = ws;                                    // [0,2048)
    int*   counts = (int*)(ws + 2048);                     // [2048,4096)
    float* sse    = ws + 4096;                             // [4096]
    float* z2     = ws + 4352;                             // [4352,69888)
    unsigned long long* rowmin_g = (unsigned long long*)(ws + 69888);  // 512 KB
    _Float16* ch  = (_Float16*)(ws + 200960);              // 1 MB
    _Float16* cl  = (_Float16*)(ws + 463104);              // 1 MB

    _Float16* zzh = (_Float16*)d_out;                      // 32 MB (overwritten by q later)
    _Float16* zzl = zzh + 16777216;                        // 32 MB

    cbnorm_zero_kernel<<<8, 256, 0, stream>>>(cb, cb2, counts, sse);
    split_c_kernel<<<512, 256, 0, stream>>>(cb, ch, cl);
    fused_z_kernel<<<2048, 256, 0, stream>>>(z, zzh, zzl, z2, rowmin_g);
    argmin_mfma_kernel<<<4096, 256, 0, stream>>>(zzh, zzl, ch, cl, cb2, z2, rowmin_g);
    gather_kernel<<<1024, 256, 0, stream>>>(z, cb, rowmin_g, out, sse, counts);
    finalize_kernel<<<1, 256, 0, stream>>>(sse, counts, out);
}

// Round 10
// 418.413 us; speedup vs baseline: 1.0805x; 1.0805x over previous
//
#include <hip/hip_runtime.h>

#define N_TOT 65536
#define K_CB  2048
#define D_DIM 256
#define HW    4096       // H*W
#define DHW   1048576    // D*H*W

typedef _Float16 half8 __attribute__((ext_vector_type(8)));
typedef _Float16 half4v __attribute__((ext_vector_type(4)));
typedef float f32x16 __attribute__((ext_vector_type(16)));

// ws layout (4-byte element offsets):
//   cb2      [0, 2048)          float (np-pairwise ||c_k||^2)
//   counts   [2048, 4096)       int
//   sse      [4096, 4098)       double (8-byte aligned at byte 16384)
//   z2       [4352, 69888)      float (np-pairwise ||z_n||^2)
//   rowmin_g [69888, 200960)    u64 x 65536
//   c_hi     [200960, 463104)   fp16 x 524288  (codebook * 2^14, hi)
//   c_lo     [463104, 725248)   fp16 x 524288  (lo)
// z splits live in d_out[0..16777216) floats (overwritten later by q), in
// FRAGMENT-MAJOR layout (dense per-wave MFMA A-loads, no LDS for A):
//   element (n,d) at half-offset rb*8192 + s*512 + lane*8 + e, where
//   rb=n>>5, s=d>>4, lane=(n&31)|(((d>>3)&1)<<5), e=d&7.
//   zh = (fp16*)d_out (z*2^11 hi), zl follows (lo).

__device__ __forceinline__ void gload_lds16(const void* g, void* l) {
    __builtin_amdgcn_global_load_lds((const __attribute__((address_space(1))) void*)g,
                                     (__attribute__((address_space(3))) void*)l, 16, 0, 0);
}

// ---------- codebook split + norms (np-pairwise) + zero counts/sse, one kernel ----------
__device__ __forceinline__ float pw128_sq(const float* __restrict__ base, int stride) {
    #pragma clang fp contract(off)
    float r[8];
    #pragma unroll
    for (int j = 0; j < 8; ++j) { float v = base[j * stride]; r[j] = v * v; }
    for (int i = 8; i < 128; i += 8) {
        #pragma unroll
        for (int j = 0; j < 8; ++j) { float v = base[(i + j) * stride]; r[j] += v * v; }
    }
    return ((r[0] + r[1]) + (r[2] + r[3])) + ((r[4] + r[5]) + (r[6] + r[7]));
}

__global__ void split_c_kernel(const float* __restrict__ cb,
                               _Float16* __restrict__ ch, _Float16* __restrict__ cl,
                               float* __restrict__ cb2, int* __restrict__ counts,
                               double* __restrict__ sse) {
    int e = (blockIdx.x * 256 + threadIdx.x) * 4;
    float4 v = *(const float4*)(cb + e);
    float xs[4] = {v.x, v.y, v.z, v.w};
    half4v hh, hl;
    #pragma unroll
    for (int u = 0; u < 4; ++u) {
        float x = xs[u] * 16384.0f;                  // 2^14 exact
        _Float16 hv = (_Float16)x;
        hh[u] = hv;
        hl[u] = (_Float16)(x - (float)hv);           // exact sub, then RTNE
    }
    *(half4v*)(ch + e) = hh;
    *(half4v*)(cl + e) = hl;
    // blocks 0..7: per-row norms (rows L2-hot from split reads) + zero counts/sse
    if (blockIdx.x < 8) {
        #pragma clang fp contract(off)
        int k = blockIdx.x * 256 + threadIdx.x;
        const float* row = cb + (size_t)k * D_DIM;
        cb2[k] = pw128_sq(row, 1) + pw128_sq(row + 128, 1);
        counts[k] = 0;
        if (k == 0) *sse = 0.0;
    }
}

// ---------- fused: z transpose+split (frag-major), np-exact z2, rowmin_g init ----------
// Block: 32 rows x 256 d. 2048 blocks x 256 threads.
__global__ void fused_z_kernel(const float* __restrict__ z,
                               _Float16* __restrict__ zh, _Float16* __restrict__ zl,
                               float* __restrict__ z2,
                               unsigned long long* __restrict__ rowmin_g) {
    __shared__ __align__(16) float lt[256 * 33];   // lt[d][n], pad stride 33
    __shared__ float rj[512];                      // [n(32)][half(2)][j(8)]
    __shared__ float hh[64];                       // [half(2)][n(32)]
    int t = threadIdx.x;
    int n0 = blockIdx.x * 32;
    int b = n0 >> 12, s0 = n0 & 4095;
    const float* zb = z + (size_t)b * DHW + s0;

    #pragma unroll
    for (int v = 0; v < 8; ++v) {                  // 2048 float4 loads
        int f = v * 256 + t;
        int d = f >> 3, nch = f & 7;
        float4 val = *(const float4*)(zb + (size_t)d * HW + nch * 4);
        lt[d * 33 + nch * 4 + 0] = val.x;
        lt[d * 33 + nch * 4 + 1] = val.y;
        lt[d * 33 + nch * 4 + 2] = val.z;
        lt[d * 33 + nch * 4 + 3] = val.w;
    }
    __syncthreads();

    // np-pairwise partials: thread (n, j) accumulates r_j over i*8+j, both halves.
    {
        #pragma clang fp contract(off)
        int n = t & 31, j = t >> 5;                // j in 0..7
        #pragma unroll
        for (int hf = 0; hf < 2; ++hf) {
            float r = 0.f;
            #pragma unroll
            for (int i = 0; i < 16; ++i) {
                float v = lt[(hf * 128 + i * 8 + j) * 33 + n];
                r += v * v;
            }
            rj[n * 16 + hf * 8 + j] = r;
        }
    }

    // split writes, FRAGMENT-MAJOR: wave wv handles slice s=v*4+wv; lane ln
    // writes the 8 halfs of (row n=ln&31, d0=s*16+(ln>>5)*8) -> dense 1KB/wave.
    {
        int wv = t >> 6, ln = t & 63;
        int rb = n0 >> 5;
        #pragma unroll
        for (int v = 0; v < 4; ++v) {
            int s = v * 4 + wv;                    // slice 0..15
            int n = ln & 31;
            int d0 = s * 16 + (ln >> 5) * 8;
            half8 hv, lv;
            #pragma unroll
            for (int u = 0; u < 8; ++u) {
                float x = lt[(d0 + u) * 33 + n] * 2048.0f;   // 2^11 exact
                _Float16 h = (_Float16)x;
                hv[u] = h;
                lv[u] = (_Float16)(x - (float)h);
            }
            size_t off = (size_t)rb * 8192 + s * 512 + ln * 8;
            *(half8*)(zh + off) = hv;
            *(half8*)(zl + off) = lv;
        }
    }
    __syncthreads();

    if (t < 64) {                                  // np combine per (n, half)
        #pragma clang fp contract(off)
        int n = t & 31, hf = t >> 5;
        const float* r = &rj[n * 16 + hf * 8];
        hh[hf * 32 + n] = ((r[0] + r[1]) + (r[2] + r[3])) + ((r[4] + r[5]) + (r[6] + r[7]));
    }
    __syncthreads();
    if (t < 32) {
        #pragma clang fp contract(off)
        z2[n0 + t] = hh[t] + hh[32 + t];           // half0 + half1, np order
        rowmin_g[n0 + t] = ~0ull;
    }
}

// ---------- MFMA distance + argmin (r8 champion, VERBATIM) ----------
// Block: 128 rows x 128 codes, 256 threads (4 waves 2Mx2N; wave 64x64, acc[2][2]).
// A never touches LDS (frag-major: one dense 1KB wave-load per fragment).
// A prefetched one tile ahead into ping-pong regs (afA/afB, static indexing).
// B staged row-major+XOR-swizzle via global_load_lds, double-buffered 2x16KB.
// ONE __syncthreads per tile (compiler-known barrier; asm variants regressed r7).
// acc = 2^25*dot; m2 = acc*2^-24 exact; score = (z2+c2) - m2 (matches np fp32).

__device__ __forceinline__ unsigned long long kmin_xor(unsigned long long key, int m) {
    unsigned lo = (unsigned)key, hi = (unsigned)(key >> 32);
    unsigned olo = __shfl_xor(lo, m);
    unsigned ohi = __shfl_xor(hi, m);
    unsigned long long o = ((unsigned long long)ohi << 32) | olo;
    return (o < key) ? o : key;
}

__launch_bounds__(256, 3)
__global__ void argmin_mfma_kernel(const _Float16* __restrict__ zhf, const _Float16* __restrict__ zlf,
                                   const _Float16* __restrict__ ch, const _Float16* __restrict__ cl,
                                   const float* __restrict__ cb2, const float* __restrict__ z2arr,
                                   unsigned long long* __restrict__ rowmin_g) {
    __shared__ __align__(16) char lds_raw[32768];
    _Float16* b0 = (_Float16*)lds_raw;               // 128 codes x 64 k (16B-unit XOR swizzle)
    _Float16* b1 = (_Float16*)(lds_raw + 16384);

    int t = threadIdx.x;
    // bijective XCD swizzle: 8192 blocks, 1024 per XCD; ct fastest within chunk so
    // the 16 B-panels (2 MB split codebook) stay L2-resident per XCD.
    int bid = blockIdx.x;
    int swz = (bid & 7) * 1024 + (bid >> 3);
    int r0 = (swz >> 4) * 128;
    int c0 = (swz & 15) * 128;
    int w = t >> 6, lane = t & 63;
    int wm = w >> 1, wn = w & 1;                 // wave -> (row half, col half)
    int l31 = lane & 31, l5 = lane >> 5;

    f32x16 acc[2][2];
    #pragma unroll
    for (int i = 0; i < 2; ++i)
        #pragma unroll
        for (int j = 0; j < 2; ++j)
            #pragma unroll
            for (int r = 0; r < 16; ++r) acc[i][j][r] = 0.f;

    float c2v[2];
    #pragma unroll
    for (int j = 0; j < 2; ++j)
        c2v[j] = cb2[c0 + wn * 64 + j * 32 + l31];

    // A-fragment bases (halfs): row-blocks rb = (r0>>5)+wm*2+i; lane-dense.
    size_t abase0 = (size_t)((r0 >> 5) + wm * 2) * 8192 + (size_t)lane * 8;
    size_t abase1 = abase0 + 8192;

    // stage B tile kt into nb (4 gload_lds16/thread, inverse-swizzled source)
    auto stage_B = [&](int kt, _Float16* nb) {
        const _Float16* bsrc = ((kt >> 2) == 1) ? cl : ch;
        int koff = (kt & 3) * 64;
        #pragma unroll
        for (int v = 0; v < 4; ++v) {            // 1024 16B-units
            int p = v * 256 + t;
            int row = p >> 3;
            int ku = (p & 7) ^ (row & 7);        // inverse swizzle on global source
            gload_lds16(bsrc + (size_t)((c0 + row) * 256 + koff + ku * 8), nb + p * 8);
        }
    };
    // load A-fragments for tile kt (8 dense 1KB wave-loads, pure register)
    auto load_A = [&](int kt, half8 (&dst)[2][4]) {
        const _Float16* as = (kt < 8) ? zhf : zlf;
        int soff = (kt & 3) * 2048;              // (kt&3)*4 slices x 512 halfs
        #pragma unroll
        for (int ks = 0; ks < 4; ++ks) {
            dst[0][ks] = *(const half8*)(as + abase0 + soff + ks * 512);
            dst[1][ks] = *(const half8*)(as + abase1 + soff + ks * 512);
        }
    };
    // compute one K-tile from LDS buffer lb and register A-frags
    auto compute = [&](const _Float16* lb, const half8 (&af)[2][4]) {
        #pragma unroll
        for (int ks = 0; ks < 4; ++ks) {
            half8 bf[2];
            #pragma unroll
            for (int j = 0; j < 2; ++j) {
                int row = wn * 64 + j * 32 + l31;
                int ku  = (ks * 2 + l5) ^ (row & 7);
                bf[j] = *(const half8*)(lb + row * 64 + ku * 8);
            }
            #pragma unroll
            for (int i = 0; i < 2; ++i)
                #pragma unroll
                for (int j = 0; j < 2; ++j)
                    acc[i][j] = __builtin_amdgcn_mfma_f32_32x32x16_f16(af[i][ks], bf[j], acc[i][j], 0, 0, 0);
        }
    };

    half8 afA[2][4], afB[2][4];

    // prologue: stage tile 0 (B->LDS, A->regs), drain once
    stage_B(0, b0);
    load_A(0, afA);
    __syncthreads();

    #pragma unroll 1
    for (int kp = 0; kp < 6; ++kp) {
        int kt1 = kp * 2 + 1;
        // even tile: issue next-tile loads first (full compute phase to land)
        stage_B(kt1, b1);
        load_A(kt1, afB);
        compute(b0, afA);
        __syncthreads();                         // drains everything; all loads old
        // odd tile
        if (kp < 5) {
            stage_B(kt1 + 1, b0);
            load_A(kt1 + 1, afA);
        }
        compute(b1, afB);
        __syncthreads();
    }

    // Epilogue. D mapping (32x32): col=lane&31, row=(reg&3)+8*(reg>>2)+4*(lane>>5).
    // Phase 1: lane j-min -> xor16 -> xor8 pair-mins -> 8 keys/row/wave into LDS.
    unsigned long long* scratch = (unsigned long long*)lds_raw;      // 128 x 18 u64
    #pragma unroll
    for (int i = 0; i < 2; ++i) {
        #pragma unroll
        for (int rg = 0; rg < 16; ++rg) {
            int rowoff = (rg & 3) + 8 * (rg >> 2) + 4 * l5;
            int m = wm * 64 + i * 32 + rowoff;
            float zz = z2arr[r0 + m];
            unsigned long long key = ~0ull;
            #pragma unroll
            for (int j = 0; j < 2; ++j) {
                float sc = (zz + c2v[j]) - acc[i][j][rg] * (1.0f / 16777216.0f);
                unsigned long long k2 = ((unsigned long long)__float_as_uint(sc) << 32)
                                      | (unsigned)(c0 + wn * 64 + j * 32 + l31);
                key = (k2 < key) ? k2 : key;      // scores > 0: raw bits orderable
            }
            key = kmin_xor(key, 16);              // stays within 32-lane m-group
            key = kmin_xor(key, 8);
            if (l31 < 8) scratch[m * 18 + wn * 8 + l31] = key;
        }
    }
    __syncthreads();
    // Phase 2: one thread per row reduces its 16 keys, one global atomic per row.
    if (t < 128) {
        const ulonglong2* srow = (const ulonglong2*)(scratch + t * 18);
        unsigned long long best = ~0ull;
        #pragma unroll
        for (int s = 0; s < 8; ++s) {
            ulonglong2 p = srow[s];
            if (p.x < best) best = p.x;
            if (p.y < best) best = p.y;
        }
        atomicMin(&rowmin_g[r0 + t], best);
    }
}

// ---------- gather q + counts + SSE-from-keys (no z re-read) ----------
// The winning key's top 32 bits ARE the row's emulated-fp32 distance ||z-c||^2,
// so SSE = sum of key-scores -- the 64 MB z re-read is eliminated. q is written
// from the L2-hot codebook only (write-bound: 64 MB). SSE accumulated in DOUBLE
// (order-insensitive to fp32 noise; strictly less summation error than r8's
// 1024-float-partial atomics). Block: 64 rows x 256 d, 256 threads.
__global__ void gather_kernel(const float* __restrict__ cb,
                              const unsigned long long* __restrict__ rowmin_g,
                              float* __restrict__ qout,
                              double* __restrict__ sse, int* __restrict__ counts) {
    __shared__ unsigned long long keys[64];
    int t = threadIdx.x;
    int n0 = blockIdx.x * 64;
    if (t < 64) {                                // wave 0 exactly
        unsigned long long k = rowmin_g[n0 + t];
        keys[t] = k;
        atomicAdd(&counts[(int)(k & 0xFFFFFFFFull)], 1);
        float sc = __uint_as_float((unsigned)(k >> 32));
        #pragma unroll
        for (int off = 32; off > 0; off >>= 1) sc += __shfl_down(sc, off, 64);
        if (t == 0) atomicAdd(sse, (double)sc);
    }
    __syncthreads();

    int sg = (t & 15) * 4;                       // 4 consecutive n's
    int dg = t >> 4;                             // 16 d's per thread
    int b = n0 >> 12, s0 = (n0 & 4095) + sg;
    float* qb = qout + (size_t)b * DHW + s0;
    const float* c0p = cb + (size_t)(unsigned)(keys[sg + 0] & 0xFFFFFFFFull) * D_DIM;
    const float* c1p = cb + (size_t)(unsigned)(keys[sg + 1] & 0xFFFFFFFFull) * D_DIM;
    const float* c2p = cb + (size_t)(unsigned)(keys[sg + 2] & 0xFFFFFFFFull) * D_DIM;
    const float* c3p = cb + (size_t)(unsigned)(keys[sg + 3] & 0xFFFFFFFFull) * D_DIM;

    #pragma unroll
    for (int dd4 = 0; dd4 < 4; ++dd4) {
        int d = dg * 16 + dd4 * 4;
        float4 cA = *(const float4*)(c0p + d);
        float4 cB = *(const float4*)(c1p + d);
        float4 cC = *(const float4*)(c2p + d);
        float4 cD = *(const float4*)(c3p + d);
        float a0[4] = {cA.x, cA.y, cA.z, cA.w};
        float a1[4] = {cB.x, cB.y, cB.z, cB.w};
        float a2[4] = {cC.x, cC.y, cC.z, cC.w};
        float a3[4] = {cD.x, cD.y, cD.z, cD.w};
        #pragma unroll
        for (int u = 0; u < 4; ++u) {
            float4 qv;
            qv.x = a0[u]; qv.y = a1[u]; qv.z = a2[u]; qv.w = a3[u];
            *(float4*)(qb + (size_t)(d + u) * HW) = qv;
        }
    }
}

__global__ void finalize_kernel(const double* __restrict__ sse, const int* __restrict__ counts,
                                float* __restrict__ out) {
    int t = threadIdx.x;
    float mse = (float)(*sse) * (1.0f / 16777216.0f);   // /(N*D)
    if (t == 0) {
        out[16777216] = mse * 1.25f;  // loss
        out[16777217] = mse;          // codebook_loss
        out[16777218] = mse;          // commitment_loss
    }
    for (int i = t; i < 2048; i += 256) out[16777219 + i] = (float)counts[i];
}

extern "C" void kernel_launch(void* const* d_in, const int* in_sizes, int n_in,
                              void* d_out, int out_size, void* d_ws, size_t ws_size,
                              hipStream_t stream) {
    const float* z  = (const float*)d_in[0];
    const float* cb = (const float*)d_in[1];
    float* out = (float*)d_out;
    float* ws  = (float*)d_ws;

    float*  cb2    = ws;                                   // [0,2048)
    int*    counts = (int*)(ws + 2048);                    // [2048,4096)
    double* sse    = (double*)(ws + 4096);                 // [4096,4098), 8B-aligned
    float*  z2     = ws + 4352;                            // [4352,69888)
    unsigned long long* rowmin_g = (unsigned long long*)(ws + 69888);  // 512 KB
    _Float16* ch  = (_Float16*)(ws + 200960);              // 1 MB
    _Float16* cl  = (_Float16*)(ws + 463104);              // 1 MB

    _Float16* zzh = (_Float16*)d_out;                      // 32 MB (overwritten by q later)
    _Float16* zzl = zzh + 16777216;                        // 32 MB

    split_c_kernel<<<512, 256, 0, stream>>>(cb, ch, cl, cb2, counts, sse);
    fused_z_kernel<<<2048, 256, 0, stream>>>(z, zzh, zzl, z2, rowmin_g);
    argmin_mfma_kernel<<<8192, 256, 0, stream>>>(zzh, zzl, ch, cl, cb2, z2, rowmin_g);
    gather_kernel<<<1024, 256, 0, stream>>>(cb, rowmin_g, out, sse, counts);
    finalize_kernel<<<1, 256, 0, stream>>>(sse, counts, out);
}